// Round 2
// baseline (510.668 us; speedup 1.0000x reference)
//
#include <hip/hip_runtime.h>

#define DIM_OUT 64
#define ALPHA 0.5f
#define BLOCK 256
#define CHUNK 32             // orders staged per LDS pass
#define LSTRIDE (CHUNK + 1)  // +1 pad: compute-phase writes & flush reads conflict-free

// One thread per row computes the serial Gegenbauer recurrence (fully unrolled,
// all i-dependent coefficients are compile-time constants). Instead of each
// thread writing its own 256B row (lane-stride-256B scatter = 64 partial-line
// transactions per store instruction), results are staged in LDS and flushed
// with coalesced wave stores: 8 consecutive lanes cover one aligned 128B row
// segment, every 64B line fully written by a single instruction.
__global__ __launch_bounds__(BLOCK) void geg_kernel(const float* __restrict__ x,
                                                    float* __restrict__ out,
                                                    int n) {
    __shared__ float lds[BLOCK * LSTRIDE];   // 256*33*4 = 33792 B -> 4 blocks/CU

    const int tid = threadIdx.x;
    const size_t base_row = (size_t)blockIdx.x * BLOCK;
    const size_t row = base_row + tid;

    const float xv = (row < (size_t)n) ? x[row] : 0.0f;

    float prev2 = 1.0f;               // C_0
    float prev  = 2.0f * ALPHA * xv;  // C_1

    float* myrow = lds + tid * LSTRIDE;

    // ---------- chunk 0: C_1 .. C_32 ----------
    myrow[0] = prev;
    #pragma unroll
    for (int i = 2; i <= CHUNK; ++i) {
        const float a   = (2.0f * (float)i - 2.0f + 2.0f * ALPHA);
        const float b   = (-(float)i + 2.0f - 2.0f * ALPHA);
        const float inv = 1.0f / (float)i;
        float ci = (a * xv * prev + b * prev2) * inv;
        prev2 = prev;
        prev  = ci;
        myrow[i - 1] = ci;            // compile-time LDS offset under unroll
    }
    __syncthreads();

    // flush chunk 0: 256 rows x 32 cols = 2048 float4, 8 per thread
    #pragma unroll
    for (int j = 0; j < 8; ++j) {
        int f   = j * BLOCK + tid;    // float4 index within the tile
        int r   = f >> 3;             // row within block (8 float4 per 128B segment)
        int c4  = f & 7;              // which float4 inside the 32-col segment
        size_t grow = base_row + r;
        if (grow < (size_t)n) {
            const float* w = lds + r * LSTRIDE + c4 * 4;
            float4 v = make_float4(w[0], w[1], w[2], w[3]);
            *(float4*)(out + grow * DIM_OUT + c4 * 4) = v;
        }
    }
    __syncthreads();   // LDS reads done before chunk 1 overwrites

    // ---------- chunk 1: C_33 .. C_64 ----------
    #pragma unroll
    for (int i = CHUNK + 1; i <= DIM_OUT; ++i) {
        const float a   = (2.0f * (float)i - 2.0f + 2.0f * ALPHA);
        const float b   = (-(float)i + 2.0f - 2.0f * ALPHA);
        const float inv = 1.0f / (float)i;
        float ci = (a * xv * prev + b * prev2) * inv;
        prev2 = prev;
        prev  = ci;
        myrow[i - 1 - CHUNK] = ci;
    }
    __syncthreads();

    // flush chunk 1 into columns 32..63
    #pragma unroll
    for (int j = 0; j < 8; ++j) {
        int f   = j * BLOCK + tid;
        int r   = f >> 3;
        int c4  = f & 7;
        size_t grow = base_row + r;
        if (grow < (size_t)n) {
            const float* w = lds + r * LSTRIDE + c4 * 4;
            float4 v = make_float4(w[0], w[1], w[2], w[3]);
            *(float4*)(out + grow * DIM_OUT + CHUNK + c4 * 4) = v;
        }
    }
}

extern "C" void kernel_launch(void* const* d_in, const int* in_sizes, int n_in,
                              void* d_out, int out_size, void* d_ws, size_t ws_size,
                              hipStream_t stream) {
    const float* x = (const float*)d_in[0];
    float* out = (float*)d_out;
    int n = in_sizes[0];   // 2,000,000 rows (x is [n,1])

    const int block = BLOCK;
    const int grid = (n + block - 1) / block;
    geg_kernel<<<grid, block, 0, stream>>>(x, out, n);
}